// Round 1
// baseline (507.283 us; speedup 1.0000x reference)
//
#include <hip/hip_runtime.h>

typedef unsigned short ushort_t;
typedef float f32x4 __attribute__((ext_vector_type(4)));
typedef short bf16x8 __attribute__((ext_vector_type(8)));

#define NB 256
#define NL 256
#define NIN 256
#define ND 128
#define NH 64
#define BL (NB * NL)                 // 65536 rows
#define BLD ((size_t)BL * ND)        // 8,388,608 elements per gate

// ---------- bf16 helpers (manual RNE, no type-support risk) ----------
__device__ __forceinline__ ushort_t bf16_rne(float v) {
  unsigned u = __float_as_uint(v);
  return (ushort_t)((u + 0x7FFFu + ((u >> 16) & 1u)) >> 16);
}
__device__ __forceinline__ float bf16_to_f32(ushort_t h) {
  return __uint_as_float(((unsigned)h) << 16);
}

// =====================================================================
// Kernel A: a[b,t] = sigmoid(x[b,t,:] . (k1 - k2))
// =====================================================================
__global__ void ka_kernel(const float* __restrict__ x,
                          const float* __restrict__ k1k2,
                          float* __restrict__ wsA) {
  int row = blockIdx.x * 256 + threadIdx.x;   // (b,t) flat
  const float4* xp = (const float4*)(x + (size_t)row * NIN);
  const float4* k1 = (const float4*)(k1k2);
  const float4* k2 = (const float4*)(k1k2 + NIN);
  float acc = 0.f;
#pragma unroll 8
  for (int i = 0; i < NIN / 4; ++i) {
    float4 xv = xp[i];
    float4 a1 = k1[i];
    float4 a2 = k2[i];
    acc += xv.x * (a1.x - a2.x) + xv.y * (a1.y - a2.y) +
           xv.z * (a1.z - a2.z) + xv.w * (a1.w - a2.w);
  }
  wsA[row] = 1.f / (1.f + __expf(-acc));
}

// =====================================================================
// Kernel B: X_g = x @ w_g^T  (no bias; bias added in scan)
// split-bf16 MFMA: X ~= xh*wh + xh*wl + xl*wh   (fp32-class accuracy)
// grid (512 row-tiles of 128, 3 gates), 256 threads (4 waves, 2x2 of 64x64)
// =====================================================================
__global__ __launch_bounds__(256, 2) void kproj_kernel(
    const float* __restrict__ x, const float* __restrict__ w_r,
    const float* __restrict__ w_z, const float* __restrict__ w_h,
    _Float16* __restrict__ wsX) {
  const int g = blockIdx.y;
  const float* w = (g == 0) ? w_r : (g == 1) ? w_z : w_h;
  const int r0 = blockIdx.x * 128;

  __shared__ ushort_t Ahi[128 * 40];
  __shared__ ushort_t Alo[128 * 40];
  __shared__ ushort_t Bhi[128 * 40];
  __shared__ ushort_t Blo[128 * 40];

  const int tid = threadIdx.x;
  const int lane = tid & 63;
  const int wv = tid >> 6;
  const int wrow = (wv >> 1) * 64;
  const int wcol = (wv & 1) * 64;
  const int fr = lane & 15;   // A row / B col / C col
  const int fg = lane >> 4;   // k-group / C row-group

  f32x4 acc[4][4];
#pragma unroll
  for (int m = 0; m < 4; ++m)
#pragma unroll
    for (int n = 0; n < 4; ++n) acc[m][n] = (f32x4){0.f, 0.f, 0.f, 0.f};

  const int srow = tid >> 1;          // 0..127
  const int kseg = (tid & 1) * 16;    // 0 or 16

  for (int kc = 0; kc < 8; ++kc) {
    const int k0 = kc * 32;
    const float4* xp = (const float4*)(x + (size_t)(r0 + srow) * NIN + k0 + kseg);
    const float4* wp = (const float4*)(w + (size_t)srow * NIN + k0 + kseg);
#pragma unroll
    for (int i = 0; i < 4; ++i) {
      float4 xv = xp[i];
      float4 wvv = wp[i];
      int base = srow * 40 + kseg + 4 * i;
      {
        ushort_t h0 = bf16_rne(xv.x), h1 = bf16_rne(xv.y),
                 h2 = bf16_rne(xv.z), h3 = bf16_rne(xv.w);
        *(ushort4*)(&Ahi[base]) = make_ushort4(h0, h1, h2, h3);
        ushort_t l0 = bf16_rne(xv.x - bf16_to_f32(h0));
        ushort_t l1 = bf16_rne(xv.y - bf16_to_f32(h1));
        ushort_t l2 = bf16_rne(xv.z - bf16_to_f32(h2));
        ushort_t l3 = bf16_rne(xv.w - bf16_to_f32(h3));
        *(ushort4*)(&Alo[base]) = make_ushort4(l0, l1, l2, l3);
      }
      {
        ushort_t h0 = bf16_rne(wvv.x), h1 = bf16_rne(wvv.y),
                 h2 = bf16_rne(wvv.z), h3 = bf16_rne(wvv.w);
        *(ushort4*)(&Bhi[base]) = make_ushort4(h0, h1, h2, h3);
        ushort_t l0 = bf16_rne(wvv.x - bf16_to_f32(h0));
        ushort_t l1 = bf16_rne(wvv.y - bf16_to_f32(h1));
        ushort_t l2 = bf16_rne(wvv.z - bf16_to_f32(h2));
        ushort_t l3 = bf16_rne(wvv.w - bf16_to_f32(h3));
        *(ushort4*)(&Blo[base]) = make_ushort4(l0, l1, l2, l3);
      }
    }
    __syncthreads();

    bf16x8 ah[4], al[4], bh[4], bl[4];
#pragma unroll
    for (int m = 0; m < 4; ++m) {
      ah[m] = *(const bf16x8*)(&Ahi[(wrow + m * 16 + fr) * 40 + 8 * fg]);
      al[m] = *(const bf16x8*)(&Alo[(wrow + m * 16 + fr) * 40 + 8 * fg]);
      bh[m] = *(const bf16x8*)(&Bhi[(wcol + m * 16 + fr) * 40 + 8 * fg]);
      bl[m] = *(const bf16x8*)(&Blo[(wcol + m * 16 + fr) * 40 + 8 * fg]);
    }
#pragma unroll
    for (int m = 0; m < 4; ++m)
#pragma unroll
      for (int n = 0; n < 4; ++n) {
        acc[m][n] = __builtin_amdgcn_mfma_f32_16x16x32_bf16(ah[m], bh[n], acc[m][n], 0, 0, 0);
        acc[m][n] = __builtin_amdgcn_mfma_f32_16x16x32_bf16(ah[m], bl[n], acc[m][n], 0, 0, 0);
        acc[m][n] = __builtin_amdgcn_mfma_f32_16x16x32_bf16(al[m], bh[n], acc[m][n], 0, 0, 0);
      }
    __syncthreads();
  }

  // epilogue: C layout col=lane&15, row=(lane>>4)*4+reg  [m89-verified]
#pragma unroll
  for (int m = 0; m < 4; ++m)
#pragma unroll
    for (int n = 0; n < 4; ++n)
#pragma unroll
      for (int r = 0; r < 4; ++r) {
        int row = r0 + wrow + m * 16 + fg * 4 + r;
        int col = wcol + n * 16 + fr;
        wsX[(size_t)g * BLD + (size_t)row * ND + col] = (_Float16)acc[m][n][r];
      }
}

// =====================================================================
// Kernel C: the sequential scan. 256 blocks (one batch each), 256 thr.
// thread: d = tid&127 (output dim), half = tid>>7 (k-half of the dots)
// u rows live in VGPRs; m_t broadcast via v_readlane; history in f16 LDS
// =====================================================================
__global__ __launch_bounds__(256, 1) void kscan_kernel(
    const float* __restrict__ u_r, const float* __restrict__ u_z,
    const float* __restrict__ u_h, const float* __restrict__ b_r,
    const float* __restrict__ b_z, const float* __restrict__ b_h,
    const int* __restrict__ cor, const _Float16* __restrict__ wsX,
    const float* __restrict__ wsA, float* __restrict__ out) {
  const int b = blockIdx.x;
  const int tid = threadIdx.x;
  const int d = tid & 127;
  const int half = tid >> 7;

  __shared__ float hprev[ND];          // h_{t-1}, fp32
  __shared__ float m_lds[ND];          // m_t for epilogue
  __shared__ float partial[3 * ND];    // upper-K partial sums
  __shared__ _Float16 buf16[257 * NH]; // history of h[:,H:] (f16)

  // ---- u rows into registers: u_g[d][64*half .. +64) ----
  float ur[64], uz[64], uh[64];
  {
    const float4* pr = (const float4*)(u_r + (size_t)d * ND + half * 64);
    const float4* pz = (const float4*)(u_z + (size_t)d * ND + half * 64);
    const float4* ph = (const float4*)(u_h + (size_t)d * ND + half * 64);
#pragma unroll
    for (int i = 0; i < 16; ++i) {
      float4 v = pr[i]; ur[4 * i] = v.x; ur[4 * i + 1] = v.y; ur[4 * i + 2] = v.z; ur[4 * i + 3] = v.w;
      float4 w = pz[i]; uz[4 * i] = w.x; uz[4 * i + 1] = w.y; uz[4 * i + 2] = w.z; uz[4 * i + 3] = w.w;
      float4 q = ph[i]; uh[4 * i] = q.x; uh[4 * i + 1] = q.y; uh[4 * i + 2] = q.z; uh[4 * i + 3] = q.w;
    }
  }
  float brd = 0.f, bzd = 0.f, bhd = 0.f;
  if (half == 0) { brd = b_r[d]; bzd = b_z[d]; bhd = b_h[d]; }

  if (tid < ND) hprev[tid] = 0.f;
  if (tid < NH) buf16[tid] = (_Float16)0.f;

  const size_t rowb = (size_t)b * NL;
  // preload t=0
  float a_c = wsA[rowb];
  int cor_c = cor[rowb];
  float xr_c = 0.f, xz_c = 0.f, xh_c = 0.f;
  if (half == 0) {
    size_t roff = rowb * ND + d;
    xr_c = (float)wsX[roff];
    xz_c = (float)wsX[BLD + roff];
    xh_c = (float)wsX[2 * BLD + roff];
  }
  __syncthreads();

  for (int t = 0; t < NL; ++t) {
    // ---- prefetch t+1 (consumed next iteration) ----
    const int tn = (t < NL - 1) ? t + 1 : NL - 1;
    float a_n = wsA[rowb + tn];
    int cor_n = cor[rowb + tn];
    float xr_n = 0.f, xz_n = 0.f, xh_n = 0.f;
    if (half == 0) {
      size_t roff = (rowb + tn) * ND + d;
      xr_n = (float)wsX[roff];
      xz_n = (float)wsX[BLD + roff];
      xh_n = (float)wsX[2 * BLD + roff];
    }

    // ---- each lane computes its own m element (lane j of wave holds m[64*half+j]) ----
    const int i_eff = (cor_c == 0) ? t : cor_c;  // block-uniform
    const int idx = (half << 6) | (tid & 63);
    float mf;
    if (half == 0) {
      mf = a_c * hprev[idx];
    } else {
      float m2 = (i_eff == t) ? hprev[idx] : (float)buf16[i_eff * NH + (idx - 64)];
      mf = (1.f - a_c) * m2;
    }
    if (tid < 64 || tid >= 192) m_lds[idx] = mf;  // wave0 -> m[0:64], wave3 -> m[64:128]

    // ---- dots: readlane broadcast of m-half, u in VGPRs ----
    float ar = 0.f, az = 0.f, ah = 0.f;
    unsigned mu = __float_as_uint(mf);
#pragma unroll
    for (int k = 0; k < 64; ++k) {
      float mk = __uint_as_float(__builtin_amdgcn_readlane(mu, k));
      ar = fmaf(mk, ur[k], ar);
      az = fmaf(mk, uz[k], az);
      ah = fmaf(mk, uh[k], ah);
    }
    if (half == 1) {
      partial[d] = ar;
      partial[ND + d] = az;
      partial[2 * ND + d] = ah;
    }
    __syncthreads();

    // ---- epilogue on half 0 ----
    if (half == 0) {
      ar += partial[d];
      az += partial[ND + d];
      ah += partial[2 * ND + d];
      float r = 1.f / (1.f + __expf(-(xr_c + brd + ar)));
      float z = 1.f / (1.f + __expf(-(xz_c + bzd + az)));
      float targ = xh_c + bhd + r * ah;
      float e2 = __expf(2.f * targ);
      float hh = (e2 - 1.f) / (e2 + 1.f);  // tanh
      float md = m_lds[d];
      float h = (1.f - z) * md + z * hh;
      out[(rowb + t) * ND + d] = h;
      hprev[d] = h;
      if (d >= NH) buf16[(t + 1) * NH + (d - NH)] = (_Float16)h;
    }

    a_c = a_n; cor_c = cor_n; xr_c = xr_n; xz_c = xz_n; xh_c = xh_n;
    __syncthreads();
  }
}

// =====================================================================
extern "C" void kernel_launch(void* const* d_in, const int* in_sizes, int n_in,
                              void* d_out, int out_size, void* d_ws, size_t ws_size,
                              hipStream_t stream) {
  (void)in_sizes; (void)n_in; (void)out_size; (void)ws_size;
  const float* x    = (const float*)d_in[0];
  const int*   cor  = (const int*)d_in[1];
  const float* w_r  = (const float*)d_in[2];
  const float* b_r  = (const float*)d_in[3];
  const float* u_r  = (const float*)d_in[4];
  const float* w_z  = (const float*)d_in[5];
  const float* b_z  = (const float*)d_in[6];
  const float* u_z  = (const float*)d_in[7];
  const float* w_h  = (const float*)d_in[8];
  const float* b_h  = (const float*)d_in[9];
  const float* u_h  = (const float*)d_in[10];
  const float* k1k2 = (const float*)d_in[11];

  _Float16* wsX = (_Float16*)d_ws;                       // 3*BL*ND f16 = 48 MB
  float* wsA = (float*)((char*)d_ws + 3 * BLD * 2);      // BL f32 = 256 KB

  ka_kernel<<<dim3(BL / 256), dim3(256), 0, stream>>>(x, k1k2, wsA);
  kproj_kernel<<<dim3(BL / 128, 3), dim3(256), 0, stream>>>(x, w_r, w_z, w_h, wsX);
  kscan_kernel<<<dim3(NB), dim3(256), 0, stream>>>(u_r, u_z, u_h, b_r, b_z, b_h,
                                                   cor, wsX, wsA, (float*)d_out);
}

// Round 2
// 489.419 us; speedup vs baseline: 1.0365x; 1.0365x over previous
//
#include <hip/hip_runtime.h>

typedef unsigned short ushort_t;
typedef float f32x4 __attribute__((ext_vector_type(4)));
typedef short bf16x8 __attribute__((ext_vector_type(8)));
typedef _Float16 f16x8 __attribute__((ext_vector_type(8)));

#define NB 256
#define NL 256
#define NIN 256
#define ND 128
#define NH 64
#define BL (NB * NL)                 // 65536 rows
#define BLD ((size_t)BL * ND)        // 8,388,608 elements per gate

// ---------- bf16 helpers (manual RNE) ----------
__device__ __forceinline__ ushort_t bf16_rne(float v) {
  unsigned u = __float_as_uint(v);
  return (ushort_t)((u + 0x7FFFu + ((u >> 16) & 1u)) >> 16);
}
__device__ __forceinline__ float bf16_to_f32(ushort_t h) {
  return __uint_as_float(((unsigned)h) << 16);
}

// =====================================================================
// Kernel A: a[b,t] = sigmoid(x[b,t,:] . (k1 - k2))   (unchanged)
// =====================================================================
__global__ void ka_kernel(const float* __restrict__ x,
                          const float* __restrict__ k1k2,
                          float* __restrict__ wsA) {
  int row = blockIdx.x * 256 + threadIdx.x;   // (b,t) flat
  const float4* xp = (const float4*)(x + (size_t)row * NIN);
  const float4* k1 = (const float4*)(k1k2);
  const float4* k2 = (const float4*)(k1k2 + NIN);
  float acc = 0.f;
#pragma unroll 8
  for (int i = 0; i < NIN / 4; ++i) {
    float4 xv = xp[i];
    float4 a1 = k1[i];
    float4 a2 = k2[i];
    acc += xv.x * (a1.x - a2.x) + xv.y * (a1.y - a2.y) +
           xv.z * (a1.z - a2.z) + xv.w * (a1.w - a2.w);
  }
  wsA[row] = 1.f / (1.f + __expf(-acc));
}

// =====================================================================
// Kernel B: X_g = x @ w_g^T (split-bf16 MFMA, unchanged this round)
// =====================================================================
__global__ __launch_bounds__(256, 2) void kproj_kernel(
    const float* __restrict__ x, const float* __restrict__ w_r,
    const float* __restrict__ w_z, const float* __restrict__ w_h,
    _Float16* __restrict__ wsX) {
  const int g = blockIdx.y;
  const float* w = (g == 0) ? w_r : (g == 1) ? w_z : w_h;
  const int r0 = blockIdx.x * 128;

  __shared__ ushort_t Ahi[128 * 40];
  __shared__ ushort_t Alo[128 * 40];
  __shared__ ushort_t Bhi[128 * 40];
  __shared__ ushort_t Blo[128 * 40];

  const int tid = threadIdx.x;
  const int lane = tid & 63;
  const int wv = tid >> 6;
  const int wrow = (wv >> 1) * 64;
  const int wcol = (wv & 1) * 64;
  const int fr = lane & 15;
  const int fg = lane >> 4;

  f32x4 acc[4][4];
#pragma unroll
  for (int m = 0; m < 4; ++m)
#pragma unroll
    for (int n = 0; n < 4; ++n) acc[m][n] = (f32x4){0.f, 0.f, 0.f, 0.f};

  const int srow = tid >> 1;
  const int kseg = (tid & 1) * 16;

  for (int kc = 0; kc < 8; ++kc) {
    const int k0 = kc * 32;
    const float4* xp = (const float4*)(x + (size_t)(r0 + srow) * NIN + k0 + kseg);
    const float4* wp = (const float4*)(w + (size_t)srow * NIN + k0 + kseg);
#pragma unroll
    for (int i = 0; i < 4; ++i) {
      float4 xv = xp[i];
      float4 wvv = wp[i];
      int base = srow * 40 + kseg + 4 * i;
      {
        ushort_t h0 = bf16_rne(xv.x), h1 = bf16_rne(xv.y),
                 h2 = bf16_rne(xv.z), h3 = bf16_rne(xv.w);
        *(ushort4*)(&Ahi[base]) = make_ushort4(h0, h1, h2, h3);
        ushort_t l0 = bf16_rne(xv.x - bf16_to_f32(h0));
        ushort_t l1 = bf16_rne(xv.y - bf16_to_f32(h1));
        ushort_t l2 = bf16_rne(xv.z - bf16_to_f32(h2));
        ushort_t l3 = bf16_rne(xv.w - bf16_to_f32(h3));
        *(ushort4*)(&Alo[base]) = make_ushort4(l0, l1, l2, l3);
      }
      {
        ushort_t h0 = bf16_rne(wvv.x), h1 = bf16_rne(wvv.y),
                 h2 = bf16_rne(wvv.z), h3 = bf16_rne(wvv.w);
        *(ushort4*)(&Bhi[base]) = make_ushort4(h0, h1, h2, h3);
        ushort_t l0 = bf16_rne(wvv.x - bf16_to_f32(h0));
        ushort_t l1 = bf16_rne(wvv.y - bf16_to_f32(h1));
        ushort_t l2 = bf16_rne(wvv.z - bf16_to_f32(h2));
        ushort_t l3 = bf16_rne(wvv.w - bf16_to_f32(h3));
        *(ushort4*)(&Blo[base]) = make_ushort4(l0, l1, l2, l3);
      }
    }
    __syncthreads();

    bf16x8 ah[4], al[4], bh[4], bl[4];
#pragma unroll
    for (int m = 0; m < 4; ++m) {
      ah[m] = *(const bf16x8*)(&Ahi[(wrow + m * 16 + fr) * 40 + 8 * fg]);
      al[m] = *(const bf16x8*)(&Alo[(wrow + m * 16 + fr) * 40 + 8 * fg]);
      bh[m] = *(const bf16x8*)(&Bhi[(wcol + m * 16 + fr) * 40 + 8 * fg]);
      bl[m] = *(const bf16x8*)(&Blo[(wcol + m * 16 + fr) * 40 + 8 * fg]);
    }
#pragma unroll
    for (int m = 0; m < 4; ++m)
#pragma unroll
      for (int n = 0; n < 4; ++n) {
        acc[m][n] = __builtin_amdgcn_mfma_f32_16x16x32_bf16(ah[m], bh[n], acc[m][n], 0, 0, 0);
        acc[m][n] = __builtin_amdgcn_mfma_f32_16x16x32_bf16(ah[m], bl[n], acc[m][n], 0, 0, 0);
        acc[m][n] = __builtin_amdgcn_mfma_f32_16x16x32_bf16(al[m], bh[n], acc[m][n], 0, 0, 0);
      }
    __syncthreads();
  }

#pragma unroll
  for (int m = 0; m < 4; ++m)
#pragma unroll
    for (int n = 0; n < 4; ++n)
#pragma unroll
      for (int r = 0; r < 4; ++r) {
        int row = r0 + wrow + m * 16 + fg * 4 + r;
        int col = wcol + n * 16 + fr;
        wsX[(size_t)g * BLD + (size_t)row * ND + col] = (_Float16)acc[m][n][r];
      }
}

// =====================================================================
// Kernel C v2: MFMA scan. 256 blocks (1 batch each), 256 threads.
// Wave w owns d in [32w,32w+32) (2 n-tiles x 3 gates = 6 accumulators).
// u fragments preloaded in VGPRs (f16); A frag (m_t) built in-register
// from LDS hprev (f32) / hist (f16). K=128 inside the accumulator ->
// no inter-wave reduction. Two barriers/step.
// =====================================================================
__global__ __launch_bounds__(256, 1) void kscan_kernel(
    const float* __restrict__ u_r, const float* __restrict__ u_z,
    const float* __restrict__ u_h, const float* __restrict__ b_r,
    const float* __restrict__ b_z, const float* __restrict__ b_h,
    const int* __restrict__ cor, const _Float16* __restrict__ wsX,
    const float* __restrict__ wsA, float* __restrict__ out) {
  const int b = blockIdx.x;
  const int tid = threadIdx.x;
  const int lane = tid & 63;
  const int w = tid >> 6;        // wave id -> d range [32w, 32w+32)
  const int quad = lane >> 4;
  const int l16 = lane & 15;
  const int q8 = quad * 8;

  __shared__ __align__(16) float hprev[ND];               // h_{t-1} fp32
  __shared__ __align__(16) _Float16 hist[(NL + 1) * NH];  // h[:,64:] history f16
  __shared__ float sA[NL];
  __shared__ int sCor[NL];

  // ---- B fragments: u_g[n][k] f16; n = 32w+16tt+l16, k = kk*32+q8+j ----
  f16x8 bf[3][2][4];
  {
    const float* us0 = u_r; const float* us1 = u_z; const float* us2 = u_h;
#pragma unroll
    for (int g = 0; g < 3; ++g) {
      const float* ug = (g == 0) ? us0 : (g == 1) ? us1 : us2;
#pragma unroll
      for (int tt = 0; tt < 2; ++tt) {
        const float* base = ug + (size_t)(32 * w + 16 * tt + l16) * ND;
#pragma unroll
        for (int kk = 0; kk < 4; ++kk) {
          const float4* p = (const float4*)(base + kk * 32 + q8);
          float4 v0 = p[0], v1 = p[1];
          f16x8 f;
          f[0] = (_Float16)v0.x; f[1] = (_Float16)v0.y;
          f[2] = (_Float16)v0.z; f[3] = (_Float16)v0.w;
          f[4] = (_Float16)v1.x; f[5] = (_Float16)v1.y;
          f[6] = (_Float16)v1.z; f[7] = (_Float16)v1.w;
          bf[g][tt][kk] = f;
        }
      }
    }
  }

  const size_t rowb = (size_t)b * NL;
  if (tid < ND) hprev[tid] = 0.f;
  if (tid < NH) hist[tid] = (_Float16)0.f;
  sA[tid] = wsA[rowb + tid];
  sCor[tid] = cor[rowb + tid];

  const int d0 = 32 * w + l16;   // tile-0 output dim
  const int d1 = d0 + 16;        // tile-1 output dim
  const bool owner = (quad == 0);

  float br0 = 0.f, br1 = 0.f, bz0 = 0.f, bz1 = 0.f, bh0 = 0.f, bh1 = 0.f;
  float xr0 = 0.f, xr1 = 0.f, xz0 = 0.f, xz1 = 0.f, xh0 = 0.f, xh1 = 0.f;
  if (owner) {
    br0 = b_r[d0]; br1 = b_r[d1];
    bz0 = b_z[d0]; bz1 = b_z[d1];
    bh0 = b_h[d0]; bh1 = b_h[d1];
    size_t ro = rowb * ND;
    xr0 = (float)wsX[ro + d0];           xr1 = (float)wsX[ro + d1];
    xz0 = (float)wsX[BLD + ro + d0];     xz1 = (float)wsX[BLD + ro + d1];
    xh0 = (float)wsX[2 * BLD + ro + d0]; xh1 = (float)wsX[2 * BLD + ro + d1];
  }
  __syncthreads();

  for (int t = 0; t < NL; ++t) {
    const float a = sA[t];
    const int c = sCor[t];
    const int ieff = (c == 0) ? t : c;    // block-uniform
    const float oma = 1.f - a;

    // ---- phase 1: all hprev/hist reads + A-frag build (pre-barrier) ----
    const float4* hp4 = (const float4*)hprev;
    f16x8 af0, af1, af2, af3;
    {
      float4 va = hp4[q8 >> 2], vb = hp4[(q8 >> 2) + 1];            // k = q8..q8+7
      float4 vc = hp4[(32 + q8) >> 2], vd = hp4[((32 + q8) >> 2) + 1];
      af0[0] = (_Float16)(a * va.x); af0[1] = (_Float16)(a * va.y);
      af0[2] = (_Float16)(a * va.z); af0[3] = (_Float16)(a * va.w);
      af0[4] = (_Float16)(a * vb.x); af0[5] = (_Float16)(a * vb.y);
      af0[6] = (_Float16)(a * vb.z); af0[7] = (_Float16)(a * vb.w);
      af1[0] = (_Float16)(a * vc.x); af1[1] = (_Float16)(a * vc.y);
      af1[2] = (_Float16)(a * vc.z); af1[3] = (_Float16)(a * vc.w);
      af1[4] = (_Float16)(a * vd.x); af1[5] = (_Float16)(a * vd.y);
      af1[6] = (_Float16)(a * vd.z); af1[7] = (_Float16)(a * vd.w);
    }
    if (ieff == t) {
      float4 va = hp4[(64 + q8) >> 2], vb = hp4[((64 + q8) >> 2) + 1];
      float4 vc = hp4[(96 + q8) >> 2], vd = hp4[((96 + q8) >> 2) + 1];
      af2[0] = (_Float16)(oma * va.x); af2[1] = (_Float16)(oma * va.y);
      af2[2] = (_Float16)(oma * va.z); af2[3] = (_Float16)(oma * va.w);
      af2[4] = (_Float16)(oma * vb.x); af2[5] = (_Float16)(oma * vb.y);
      af2[6] = (_Float16)(oma * vb.z); af2[7] = (_Float16)(oma * vb.w);
      af3[0] = (_Float16)(oma * vc.x); af3[1] = (_Float16)(oma * vc.y);
      af3[2] = (_Float16)(oma * vc.z); af3[3] = (_Float16)(oma * vc.w);
      af3[4] = (_Float16)(oma * vd.x); af3[5] = (_Float16)(oma * vd.y);
      af3[6] = (_Float16)(oma * vd.z); af3[7] = (_Float16)(oma * vd.w);
    } else {
      f16x8 h2 = *(const f16x8*)&hist[ieff * NH + q8];
      f16x8 h3 = *(const f16x8*)&hist[ieff * NH + 32 + q8];
#pragma unroll
      for (int j = 0; j < 8; ++j) {
        af2[j] = (_Float16)(oma * (float)h2[j]);
        af3[j] = (_Float16)(oma * (float)h3[j]);
      }
    }
    // epilogue m pre-read (block-broadcast addresses; valid for owners)
    float md0, md1;
    if (w < 2) {
      md0 = a * hprev[d0]; md1 = a * hprev[d1];
    } else if (ieff == t) {
      md0 = oma * hprev[d0]; md1 = oma * hprev[d1];
    } else {
      md0 = oma * (float)hist[ieff * NH + (d0 - NH)];
      md1 = oma * (float)hist[ieff * NH + (d1 - NH)];
    }
    __syncthreads();   // B1: all reads done before any epilogue write

    // ---- phase 2: MFMA (K=128 folded into accumulator) ----
    f32x4 acc[3][2];
#pragma unroll
    for (int g = 0; g < 3; ++g)
#pragma unroll
      for (int tt = 0; tt < 2; ++tt) acc[g][tt] = (f32x4){0.f, 0.f, 0.f, 0.f};
#pragma unroll
    for (int g = 0; g < 3; ++g)
#pragma unroll
      for (int tt = 0; tt < 2; ++tt) {
        acc[g][tt] = __builtin_amdgcn_mfma_f32_16x16x32_f16(af0, bf[g][tt][0], acc[g][tt], 0, 0, 0);
        acc[g][tt] = __builtin_amdgcn_mfma_f32_16x16x32_f16(af1, bf[g][tt][1], acc[g][tt], 0, 0, 0);
        acc[g][tt] = __builtin_amdgcn_mfma_f32_16x16x32_f16(af2, bf[g][tt][2], acc[g][tt], 0, 0, 0);
        acc[g][tt] = __builtin_amdgcn_mfma_f32_16x16x32_f16(af3, bf[g][tt][3], acc[g][tt], 0, 0, 0);
      }

    // ---- prefetch X for t+1 (consumed next iteration) ----
    const int tn = (t < NL - 1) ? t + 1 : t;
    float nxr0 = 0.f, nxr1 = 0.f, nxz0 = 0.f, nxz1 = 0.f, nxh0 = 0.f, nxh1 = 0.f;
    if (owner) {
      size_t ro = (rowb + tn) * ND;
      nxr0 = (float)wsX[ro + d0];           nxr1 = (float)wsX[ro + d1];
      nxz0 = (float)wsX[BLD + ro + d0];     nxz1 = (float)wsX[BLD + ro + d1];
      nxh0 = (float)wsX[2 * BLD + ro + d0]; nxh1 = (float)wsX[2 * BLD + ro + d1];
    }

    // ---- epilogue: lanes 0..15 of each wave, rows = M-row 0 -> acc[..][0] ----
    if (owner) {
      {
        float rr = 1.f / (1.f + __expf(-(xr0 + br0 + acc[0][0][0])));
        float zz = 1.f / (1.f + __expf(-(xz0 + bz0 + acc[1][0][0])));
        float e2 = __expf(2.f * (xh0 + bh0 + rr * acc[2][0][0]));
        float hh = (e2 - 1.f) / (e2 + 1.f);
        float h = (1.f - zz) * md0 + zz * hh;
        out[(rowb + t) * ND + d0] = h;
        hprev[d0] = h;
        if (d0 >= NH) hist[(t + 1) * NH + (d0 - NH)] = (_Float16)h;
      }
      {
        float rr = 1.f / (1.f + __expf(-(xr1 + br1 + acc[0][1][0])));
        float zz = 1.f / (1.f + __expf(-(xz1 + bz1 + acc[1][1][0])));
        float e2 = __expf(2.f * (xh1 + bh1 + rr * acc[2][1][0]));
        float hh = (e2 - 1.f) / (e2 + 1.f);
        float h = (1.f - zz) * md1 + zz * hh;
        out[(rowb + t) * ND + d1] = h;
        hprev[d1] = h;
        if (d1 >= NH) hist[(t + 1) * NH + (d1 - NH)] = (_Float16)h;
      }
    }
    __syncthreads();   // B2: epilogue writes visible to next step

    xr0 = nxr0; xr1 = nxr1; xz0 = nxz0; xz1 = nxz1; xh0 = nxh0; xh1 = nxh1;
  }
}

// =====================================================================
extern "C" void kernel_launch(void* const* d_in, const int* in_sizes, int n_in,
                              void* d_out, int out_size, void* d_ws, size_t ws_size,
                              hipStream_t stream) {
  (void)in_sizes; (void)n_in; (void)out_size; (void)ws_size;
  const float* x    = (const float*)d_in[0];
  const int*   cor  = (const int*)d_in[1];
  const float* w_r  = (const float*)d_in[2];
  const float* b_r  = (const float*)d_in[3];
  const float* u_r  = (const float*)d_in[4];
  const float* w_z  = (const float*)d_in[5];
  const float* b_z  = (const float*)d_in[6];
  const float* u_z  = (const float*)d_in[7];
  const float* w_h  = (const float*)d_in[8];
  const float* b_h  = (const float*)d_in[9];
  const float* u_h  = (const float*)d_in[10];
  const float* k1k2 = (const float*)d_in[11];

  _Float16* wsX = (_Float16*)d_ws;                       // 3*BL*ND f16 = 48 MB
  float* wsA = (float*)((char*)d_ws + 3 * BLD * 2);      // BL f32 = 256 KB

  ka_kernel<<<dim3(BL / 256), dim3(256), 0, stream>>>(x, k1k2, wsA);
  kproj_kernel<<<dim3(BL / 128, 3), dim3(256), 0, stream>>>(x, w_r, w_z, w_h, wsX);
  kscan_kernel<<<dim3(NB), dim3(256), 0, stream>>>(u_r, u_z, u_h, b_r, b_z, b_h,
                                                   cor, wsX, wsA, (float*)d_out);
}

// Round 3
// 425.082 us; speedup vs baseline: 1.1934x; 1.1514x over previous
//
#include <hip/hip_runtime.h>

typedef unsigned short ushort_t;
typedef float f32x4 __attribute__((ext_vector_type(4)));
typedef short bf16x8 __attribute__((ext_vector_type(8)));
typedef _Float16 f16x8 __attribute__((ext_vector_type(8)));

#define NB 256
#define NL 256
#define NIN 256
#define ND 128
#define NH 64
#define BL (NB * NL)                 // 65536 rows
#define BLD ((size_t)BL * ND)        // 8,388,608 elements per gate
#define CH 16                        // X-staging chunk (steps)

// ---------- bf16 helpers (manual RNE) ----------
__device__ __forceinline__ ushort_t bf16_rne(float v) {
  unsigned u = __float_as_uint(v);
  return (ushort_t)((u + 0x7FFFu + ((u >> 16) & 1u)) >> 16);
}
__device__ __forceinline__ float bf16_to_f32(ushort_t h) {
  return __uint_as_float(((unsigned)h) << 16);
}

__device__ __forceinline__ void gload_lds16(const _Float16* gp, _Float16* lp) {
  __builtin_amdgcn_global_load_lds(
      (const __attribute__((address_space(1))) void*)gp,
      (__attribute__((address_space(3))) void*)lp, 16, 0, 0);
}

// =====================================================================
// Kernel A: a[b,t] = sigmoid(x[b,t,:] . (k1 - k2))   (unchanged)
// =====================================================================
__global__ void ka_kernel(const float* __restrict__ x,
                          const float* __restrict__ k1k2,
                          float* __restrict__ wsA) {
  int row = blockIdx.x * 256 + threadIdx.x;
  const float4* xp = (const float4*)(x + (size_t)row * NIN);
  const float4* k1 = (const float4*)(k1k2);
  const float4* k2 = (const float4*)(k1k2 + NIN);
  float acc = 0.f;
#pragma unroll 8
  for (int i = 0; i < NIN / 4; ++i) {
    float4 xv = xp[i];
    float4 a1 = k1[i];
    float4 a2 = k2[i];
    acc += xv.x * (a1.x - a2.x) + xv.y * (a1.y - a2.y) +
           xv.z * (a1.z - a2.z) + xv.w * (a1.w - a2.w);
  }
  wsA[row] = 1.f / (1.f + __expf(-acc));
}

// =====================================================================
// Kernel B: X_g = x @ w_g^T (split-bf16 MFMA, unchanged this round)
// =====================================================================
__global__ __launch_bounds__(256, 2) void kproj_kernel(
    const float* __restrict__ x, const float* __restrict__ w_r,
    const float* __restrict__ w_z, const float* __restrict__ w_h,
    _Float16* __restrict__ wsX) {
  const int g = blockIdx.y;
  const float* w = (g == 0) ? w_r : (g == 1) ? w_z : w_h;
  const int r0 = blockIdx.x * 128;

  __shared__ ushort_t Ahi[128 * 40];
  __shared__ ushort_t Alo[128 * 40];
  __shared__ ushort_t Bhi[128 * 40];
  __shared__ ushort_t Blo[128 * 40];

  const int tid = threadIdx.x;
  const int lane = tid & 63;
  const int wv = tid >> 6;
  const int wrow = (wv >> 1) * 64;
  const int wcol = (wv & 1) * 64;
  const int fr = lane & 15;
  const int fg = lane >> 4;

  f32x4 acc[4][4];
#pragma unroll
  for (int m = 0; m < 4; ++m)
#pragma unroll
    for (int n = 0; n < 4; ++n) acc[m][n] = (f32x4){0.f, 0.f, 0.f, 0.f};

  const int srow = tid >> 1;
  const int kseg = (tid & 1) * 16;

  for (int kc = 0; kc < 8; ++kc) {
    const int k0 = kc * 32;
    const float4* xp = (const float4*)(x + (size_t)(r0 + srow) * NIN + k0 + kseg);
    const float4* wp = (const float4*)(w + (size_t)srow * NIN + k0 + kseg);
#pragma unroll
    for (int i = 0; i < 4; ++i) {
      float4 xv = xp[i];
      float4 wvv = wp[i];
      int base = srow * 40 + kseg + 4 * i;
      {
        ushort_t h0 = bf16_rne(xv.x), h1 = bf16_rne(xv.y),
                 h2 = bf16_rne(xv.z), h3 = bf16_rne(xv.w);
        *(ushort4*)(&Ahi[base]) = make_ushort4(h0, h1, h2, h3);
        ushort_t l0 = bf16_rne(xv.x - bf16_to_f32(h0));
        ushort_t l1 = bf16_rne(xv.y - bf16_to_f32(h1));
        ushort_t l2 = bf16_rne(xv.z - bf16_to_f32(h2));
        ushort_t l3 = bf16_rne(xv.w - bf16_to_f32(h3));
        *(ushort4*)(&Alo[base]) = make_ushort4(l0, l1, l2, l3);
      }
      {
        ushort_t h0 = bf16_rne(wvv.x), h1 = bf16_rne(wvv.y),
                 h2 = bf16_rne(wvv.z), h3 = bf16_rne(wvv.w);
        *(ushort4*)(&Bhi[base]) = make_ushort4(h0, h1, h2, h3);
        ushort_t l0 = bf16_rne(wvv.x - bf16_to_f32(h0));
        ushort_t l1 = bf16_rne(wvv.y - bf16_to_f32(h1));
        ushort_t l2 = bf16_rne(wvv.z - bf16_to_f32(h2));
        ushort_t l3 = bf16_rne(wvv.w - bf16_to_f32(h3));
        *(ushort4*)(&Blo[base]) = make_ushort4(l0, l1, l2, l3);
      }
    }
    __syncthreads();

    bf16x8 ah[4], al[4], bh[4], bl[4];
#pragma unroll
    for (int m = 0; m < 4; ++m) {
      ah[m] = *(const bf16x8*)(&Ahi[(wrow + m * 16 + fr) * 40 + 8 * fg]);
      al[m] = *(const bf16x8*)(&Alo[(wrow + m * 16 + fr) * 40 + 8 * fg]);
      bh[m] = *(const bf16x8*)(&Bhi[(wcol + m * 16 + fr) * 40 + 8 * fg]);
      bl[m] = *(const bf16x8*)(&Blo[(wcol + m * 16 + fr) * 40 + 8 * fg]);
    }
#pragma unroll
    for (int m = 0; m < 4; ++m)
#pragma unroll
      for (int n = 0; n < 4; ++n) {
        acc[m][n] = __builtin_amdgcn_mfma_f32_16x16x32_bf16(ah[m], bh[n], acc[m][n], 0, 0, 0);
        acc[m][n] = __builtin_amdgcn_mfma_f32_16x16x32_bf16(ah[m], bl[n], acc[m][n], 0, 0, 0);
        acc[m][n] = __builtin_amdgcn_mfma_f32_16x16x32_bf16(al[m], bh[n], acc[m][n], 0, 0, 0);
      }
    __syncthreads();
  }

#pragma unroll
  for (int m = 0; m < 4; ++m)
#pragma unroll
    for (int n = 0; n < 4; ++n)
#pragma unroll
      for (int r = 0; r < 4; ++r) {
        int row = r0 + wrow + m * 16 + fg * 4 + r;
        int col = wcol + n * 16 + fr;
        wsX[(size_t)g * BLD + (size_t)row * ND + col] = (_Float16)acc[m][n][r];
      }
}

// =====================================================================
// Kernel C v3: MFMA scan, 1 barrier/step, async-chunked X, zero-VALU A-frags.
// dots split lo/hi K: d = a*lo + (1-a)*hi  (MFMA linearity; no per-step scale)
// =====================================================================
__global__ __launch_bounds__(256, 1) void kscan_kernel(
    const float* __restrict__ u_r, const float* __restrict__ u_z,
    const float* __restrict__ u_h, const float* __restrict__ b_r,
    const float* __restrict__ b_z, const float* __restrict__ b_h,
    const int* __restrict__ cor, const _Float16* __restrict__ wsX,
    const float* __restrict__ wsA, float* __restrict__ out) {
  const int b = blockIdx.x;
  const int tid = threadIdx.x;
  const int lane = tid & 63;
  const int w = tid >> 6;        // wave id -> d range [32w, 32w+32)
  const int quad = lane >> 4;
  const int l16 = lane & 15;
  const int q8 = quad * 8;

  __shared__ __align__(16) _Float16 hist[(NL + 1) * NH];   // 32896 B: h[:,64:] history
  __shared__ __align__(16) _Float16 Xl[2 * 3 * CH * ND];   // 24576 B: X dbuf
  __shared__ __align__(16) float hprev32[2][ND];           // 1024 B (parity)
  __shared__ __align__(16) _Float16 hprev16[2][NH];        // 256 B: h[:64] f16 (parity)
  __shared__ float sA[NL];
  __shared__ int sCor[NL];

  // ---- B fragments: u_g[n][k] f16; n = 32w+16tt+l16, k = kk*32+q8+j ----
  f16x8 bf[3][2][4];
#pragma unroll
  for (int g = 0; g < 3; ++g) {
    const float* ug = (g == 0) ? u_r : (g == 1) ? u_z : u_h;
#pragma unroll
    for (int tt = 0; tt < 2; ++tt) {
      const float* base = ug + (size_t)(32 * w + 16 * tt + l16) * ND;
#pragma unroll
      for (int kk = 0; kk < 4; ++kk) {
        const float4* p = (const float4*)(base + kk * 32 + q8);
        float4 v0 = p[0], v1 = p[1];
        f16x8 f;
        f[0] = (_Float16)v0.x; f[1] = (_Float16)v0.y;
        f[2] = (_Float16)v0.z; f[3] = (_Float16)v0.w;
        f[4] = (_Float16)v1.x; f[5] = (_Float16)v1.y;
        f[6] = (_Float16)v1.z; f[7] = (_Float16)v1.w;
        bf[g][tt][kk] = f;
      }
    }
  }

  const size_t rowb = (size_t)b * NL;
  if (tid < ND) { hprev32[0][tid] = 0.f; }
  if (tid < NH) { hprev16[0][tid] = (_Float16)0.f; hist[tid] = (_Float16)0.f; }
  sA[tid] = wsA[rowb + tid];
  sCor[tid] = cor[rowb + tid];

  // ---- chunk 0 of X into Xl buf 0 (wave g loads gate g; 4x 1KB each) ----
  if (w < 3) {
    const _Float16* src = wsX + (size_t)w * BLD + rowb * ND + lane * 8;
    _Float16* dst = &Xl[w * (CH * ND)];
#pragma unroll
    for (int i = 0; i < 4; ++i)
      gload_lds16(src + i * 512, dst + i * 512);
  }

  const bool owner = (quad == 0);
  const int dd[2] = {32 * w + l16, 32 * w + l16 + 16};
  float bb[3][2] = {{0.f, 0.f}, {0.f, 0.f}, {0.f, 0.f}};
  if (owner) {
    bb[0][0] = b_r[dd[0]]; bb[0][1] = b_r[dd[1]];
    bb[1][0] = b_z[dd[0]]; bb[1][1] = b_z[dd[1]];
    bb[2][0] = b_h[dd[0]]; bb[2][1] = b_h[dd[1]];
  }
  __syncthreads();   // drains chunk-0 loads (vmcnt(0) before s_barrier)

  for (int t = 0; t < NL; ++t) {
    const int par = t & 1;
    const float a = sA[t];
    const float oma = 1.f - a;
    const int c = sCor[t];
    const int ieff = (c == 0) ? t : c;    // block-uniform
    const int cur = (t >> 4) & 1;
    const int tin = t & 15;

    // ---- issue next X chunk (once per 16 steps; drained at this step's barrier)
    if ((t & 15) == 0 && t + CH < NL && w < 3) {
      const _Float16* src = wsX + (size_t)w * BLD + (rowb + t + CH) * ND + lane * 8;
      _Float16* dst = &Xl[(cur ^ 1) * (3 * CH * ND) + w * (CH * ND)];
#pragma unroll
      for (int i = 0; i < 4; ++i)
        gload_lds16(src + i * 512, dst + i * 512);
    }

    // ---- A frags: pure ds_read_b128, no VALU ----
    f16x8 af0 = *(const f16x8*)&hprev16[par][q8];          // k = q8..q8+7
    f16x8 af1 = *(const f16x8*)&hprev16[par][32 + q8];     // k = 32+q8..
    f16x8 af2 = *(const f16x8*)&hist[ieff * NH + q8];      // k = 64+q8..
    f16x8 af3 = *(const f16x8*)&hist[ieff * NH + 32 + q8]; // k = 96+q8..

    // ---- X + md reads for this step (owner lanes; from LDS) ----
    float xv[3][2], md[2];
    if (owner) {
      const _Float16* xp = &Xl[cur * (3 * CH * ND) + tin * ND];
#pragma unroll
      for (int g = 0; g < 3; ++g) {
        xv[g][0] = (float)xp[g * (CH * ND) + dd[0]];
        xv[g][1] = (float)xp[g * (CH * ND) + dd[1]];
      }
      if (w < 2) {
        md[0] = a * hprev32[par][dd[0]];
        md[1] = a * hprev32[par][dd[1]];
      } else if (ieff == t) {
        md[0] = oma * hprev32[par][dd[0]];
        md[1] = oma * hprev32[par][dd[1]];
      } else {
        md[0] = oma * (float)hist[ieff * NH + (dd[0] - NH)];
        md[1] = oma * (float)hist[ieff * NH + (dd[1] - NH)];
      }
    }

    // ---- MFMA: lo (k<64) and hi (k>=64) accumulators, depth-2 chains ----
    f32x4 accL[3][2], accH[3][2];
#pragma unroll
    for (int g = 0; g < 3; ++g)
#pragma unroll
      for (int tt = 0; tt < 2; ++tt) {
        accL[g][tt] = (f32x4){0.f, 0.f, 0.f, 0.f};
        accH[g][tt] = (f32x4){0.f, 0.f, 0.f, 0.f};
      }
#pragma unroll
    for (int g = 0; g < 3; ++g)
#pragma unroll
      for (int tt = 0; tt < 2; ++tt) {
        accL[g][tt] = __builtin_amdgcn_mfma_f32_16x16x32_f16(af0, bf[g][tt][0], accL[g][tt], 0, 0, 0);
        accH[g][tt] = __builtin_amdgcn_mfma_f32_16x16x32_f16(af2, bf[g][tt][2], accH[g][tt], 0, 0, 0);
        accL[g][tt] = __builtin_amdgcn_mfma_f32_16x16x32_f16(af1, bf[g][tt][1], accL[g][tt], 0, 0, 0);
        accH[g][tt] = __builtin_amdgcn_mfma_f32_16x16x32_f16(af3, bf[g][tt][3], accH[g][tt], 0, 0, 0);
      }

    // ---- epilogue (owner lanes; output row 0 => quad 0, reg 0) ----
    if (owner) {
#pragma unroll
      for (int tt = 0; tt < 2; ++tt) {
        float dr = a * accL[0][tt][0] + oma * accH[0][tt][0];
        float dz = a * accL[1][tt][0] + oma * accH[1][tt][0];
        float dh = a * accL[2][tt][0] + oma * accH[2][tt][0];
        float rr = 1.f / (1.f + __expf(-(xv[0][tt] + bb[0][tt] + dr)));
        float zz = 1.f / (1.f + __expf(-(xv[1][tt] + bb[1][tt] + dz)));
        float e2 = __expf(2.f * (xv[2][tt] + bb[2][tt] + rr * dh));
        float hh = (e2 - 1.f) / (e2 + 1.f);
        float h = (1.f - zz) * md[tt] + zz * hh;
        int d = dd[tt];
        out[(rowb + t) * ND + d] = h;
        hprev32[par ^ 1][d] = h;
        if (d < NH) hprev16[par ^ 1][d] = (_Float16)h;
        else        hist[(t + 1) * NH + (d - NH)] = (_Float16)h;
      }
    }
    __syncthreads();   // single barrier: step-t writes -> step-t+1 reads
  }
}

// =====================================================================
extern "C" void kernel_launch(void* const* d_in, const int* in_sizes, int n_in,
                              void* d_out, int out_size, void* d_ws, size_t ws_size,
                              hipStream_t stream) {
  (void)in_sizes; (void)n_in; (void)out_size; (void)ws_size;
  const float* x    = (const float*)d_in[0];
  const int*   cor  = (const int*)d_in[1];
  const float* w_r  = (const float*)d_in[2];
  const float* b_r  = (const float*)d_in[3];
  const float* u_r  = (const float*)d_in[4];
  const float* w_z  = (const float*)d_in[5];
  const float* b_z  = (const float*)d_in[6];
  const float* u_z  = (const float*)d_in[7];
  const float* w_h  = (const float*)d_in[8];
  const float* b_h  = (const float*)d_in[9];
  const float* u_h  = (const float*)d_in[10];
  const float* k1k2 = (const float*)d_in[11];

  _Float16* wsX = (_Float16*)d_ws;                       // 3*BL*ND f16 = 48 MB
  float* wsA = (float*)((char*)d_ws + 3 * BLD * 2);      // BL f32 = 256 KB

  ka_kernel<<<dim3(BL / 256), dim3(256), 0, stream>>>(x, k1k2, wsA);
  kproj_kernel<<<dim3(BL / 128, 3), dim3(256), 0, stream>>>(x, w_r, w_z, w_h, wsX);
  kscan_kernel<<<dim3(NB), dim3(256), 0, stream>>>(u_r, u_z, u_h, b_r, b_z, b_h,
                                                   cor, wsX, wsA, (float*)d_out);
}

// Round 4
// 401.437 us; speedup vs baseline: 1.2637x; 1.0589x over previous
//
#include <hip/hip_runtime.h>

typedef unsigned short ushort_t;
typedef float f32x4 __attribute__((ext_vector_type(4)));
typedef _Float16 f16x8 __attribute__((ext_vector_type(8)));
typedef _Float16 f16x4 __attribute__((ext_vector_type(4)));

#define NB 256
#define NL 256
#define NIN 256
#define ND 128
#define NH 64
#define BL (NB * NL)                 // 65536 rows
#define BLD ((size_t)BL * ND)        // 8,388,608 elements per gate
#define CH 16                        // X-staging chunk (steps)

// raw barrier: LDS-only drain (no vmcnt!) — global stores/loads float free
#define BAR_LDS() asm volatile("s_waitcnt lgkmcnt(0)\n\ts_barrier" ::: "memory")
#define WAIT_VM0() asm volatile("s_waitcnt vmcnt(0)" ::: "memory")

__device__ __forceinline__ void gload_lds16(const _Float16* gp, _Float16* lp) {
  __builtin_amdgcn_global_load_lds(
      (const __attribute__((address_space(1))) void*)gp,
      (__attribute__((address_space(3))) void*)lp, 16, 0, 0);
}

// =====================================================================
// Kernel A: a[b,t] = sigmoid(x[b,t,:] . (k1 - k2))   (unchanged)
// =====================================================================
__global__ void ka_kernel(const float* __restrict__ x,
                          const float* __restrict__ k1k2,
                          float* __restrict__ wsA) {
  int row = blockIdx.x * 256 + threadIdx.x;
  const float4* xp = (const float4*)(x + (size_t)row * NIN);
  const float4* k1 = (const float4*)(k1k2);
  const float4* k2 = (const float4*)(k1k2 + NIN);
  float acc = 0.f;
#pragma unroll 8
  for (int i = 0; i < NIN / 4; ++i) {
    float4 xv = xp[i];
    float4 a1 = k1[i];
    float4 a2 = k2[i];
    acc += xv.x * (a1.x - a2.x) + xv.y * (a1.y - a2.y) +
           xv.z * (a1.z - a2.z) + xv.w * (a1.w - a2.w);
  }
  wsA[row] = 1.f / (1.f + __expf(-acc));
}

// =====================================================================
// Kernel B v2: X_g = x @ w_g^T, single-term f16 MFMA (wsX is f16 anyway;
// in-dot f16 rounding adds ~5e-4 abs). Half the staging, 1/3 the MFMA.
// =====================================================================
__global__ __launch_bounds__(256, 2) void kproj_kernel(
    const float* __restrict__ x, const float* __restrict__ w_r,
    const float* __restrict__ w_z, const float* __restrict__ w_h,
    _Float16* __restrict__ wsX) {
  const int g = blockIdx.y;
  const float* w = (g == 0) ? w_r : (g == 1) ? w_z : w_h;
  const int r0 = blockIdx.x * 128;

  __shared__ __align__(16) _Float16 Ah[128 * 40];
  __shared__ __align__(16) _Float16 Bh[128 * 40];

  const int tid = threadIdx.x;
  const int lane = tid & 63;
  const int wv = tid >> 6;
  const int wrow = (wv >> 1) * 64;
  const int wcol = (wv & 1) * 64;
  const int fr = lane & 15;
  const int fg = lane >> 4;

  f32x4 acc[4][4];
#pragma unroll
  for (int m = 0; m < 4; ++m)
#pragma unroll
    for (int n = 0; n < 4; ++n) acc[m][n] = (f32x4){0.f, 0.f, 0.f, 0.f};

  const int srow = tid >> 1;
  const int kseg = (tid & 1) * 16;

  for (int kc = 0; kc < 8; ++kc) {
    const int k0 = kc * 32;
    const float4* xp = (const float4*)(x + (size_t)(r0 + srow) * NIN + k0 + kseg);
    const float4* wp = (const float4*)(w + (size_t)srow * NIN + k0 + kseg);
#pragma unroll
    for (int i = 0; i < 4; ++i) {
      float4 xv = xp[i];
      float4 wvv = wp[i];
      int base = srow * 40 + kseg + 4 * i;
      f16x4 av, bv;
      av[0] = (_Float16)xv.x;  av[1] = (_Float16)xv.y;
      av[2] = (_Float16)xv.z;  av[3] = (_Float16)xv.w;
      bv[0] = (_Float16)wvv.x; bv[1] = (_Float16)wvv.y;
      bv[2] = (_Float16)wvv.z; bv[3] = (_Float16)wvv.w;
      *(f16x4*)(&Ah[base]) = av;
      *(f16x4*)(&Bh[base]) = bv;
    }
    __syncthreads();

    f16x8 a4[4], b4[4];
#pragma unroll
    for (int m = 0; m < 4; ++m) {
      a4[m] = *(const f16x8*)(&Ah[(wrow + m * 16 + fr) * 40 + 8 * fg]);
      b4[m] = *(const f16x8*)(&Bh[(wcol + m * 16 + fr) * 40 + 8 * fg]);
    }
#pragma unroll
    for (int m = 0; m < 4; ++m)
#pragma unroll
      for (int n = 0; n < 4; ++n)
        acc[m][n] = __builtin_amdgcn_mfma_f32_16x16x32_f16(a4[m], b4[n], acc[m][n], 0, 0, 0);
    __syncthreads();
  }

#pragma unroll
  for (int m = 0; m < 4; ++m)
#pragma unroll
    for (int n = 0; n < 4; ++n)
#pragma unroll
      for (int r = 0; r < 4; ++r) {
        int row = r0 + wrow + m * 16 + fg * 4 + r;
        int col = wcol + n * 16 + fr;
        wsX[(size_t)g * BLD + (size_t)row * ND + col] = (_Float16)acc[m][n][r];
      }
}

// =====================================================================
// Kernel C v4: MFMA scan, raw s_barrier (LDS-only drain), pipelined
// (a, cor, ieff, hist-frag) state, async-chunked X.
// =====================================================================
__global__ __launch_bounds__(256, 1) void kscan_kernel(
    const float* __restrict__ u_r, const float* __restrict__ u_z,
    const float* __restrict__ u_h, const float* __restrict__ b_r,
    const float* __restrict__ b_z, const float* __restrict__ b_h,
    const int* __restrict__ cor, const _Float16* __restrict__ wsX,
    const float* __restrict__ wsA, float* __restrict__ out) {
  const int b = blockIdx.x;
  const int tid = threadIdx.x;
  const int lane = tid & 63;
  const int w = tid >> 6;        // wave id -> d range [32w, 32w+32)
  const int quad = lane >> 4;
  const int l16 = lane & 15;
  const int q8 = quad * 8;

  __shared__ __align__(16) _Float16 hist[(NL + 1) * NH];   // 32896 B
  __shared__ __align__(16) _Float16 Xl[2 * 3 * CH * ND];   // 24576 B
  __shared__ __align__(16) float hprev32[2][ND];           // 1024 B (parity)
  __shared__ __align__(16) _Float16 hprev16[2][NH];        // 256 B (parity)
  __shared__ float sA[NL];
  __shared__ int sCor[NL];

  // ---- B fragments: u_g[n][k] f16; n = 32w+16tt+l16, k = kk*32+q8+j ----
  f16x8 bf[3][2][4];
#pragma unroll
  for (int g = 0; g < 3; ++g) {
    const float* ug = (g == 0) ? u_r : (g == 1) ? u_z : u_h;
#pragma unroll
    for (int tt = 0; tt < 2; ++tt) {
      const float* base = ug + (size_t)(32 * w + 16 * tt + l16) * ND;
#pragma unroll
      for (int kk = 0; kk < 4; ++kk) {
        const float4* p = (const float4*)(base + kk * 32 + q8);
        float4 v0 = p[0], v1 = p[1];
        f16x8 f;
        f[0] = (_Float16)v0.x; f[1] = (_Float16)v0.y;
        f[2] = (_Float16)v0.z; f[3] = (_Float16)v0.w;
        f[4] = (_Float16)v1.x; f[5] = (_Float16)v1.y;
        f[6] = (_Float16)v1.z; f[7] = (_Float16)v1.w;
        bf[g][tt][kk] = f;
      }
    }
  }

  const size_t rowb = (size_t)b * NL;
  if (tid < ND) { hprev32[0][tid] = 0.f; }
  if (tid < NH) { hprev16[0][tid] = (_Float16)0.f; hist[tid] = (_Float16)0.f; }
  sA[tid] = wsA[rowb + tid];
  sCor[tid] = cor[rowb + tid];

  // ---- chunk 0 of X into Xl buf 0 (wave g loads gate g; 4x 1KB each) ----
  if (w < 3) {
    const _Float16* src = wsX + (size_t)w * BLD + rowb * ND + lane * 8;
    _Float16* dst = &Xl[w * (CH * ND)];
#pragma unroll
    for (int i = 0; i < 4; ++i)
      gload_lds16(src + i * 512, dst + i * 512);
  }

  const bool owner = (quad == 0);
  const int dd[2] = {32 * w + l16, 32 * w + l16 + 16};
  float bb[3][2] = {{0.f, 0.f}, {0.f, 0.f}, {0.f, 0.f}};
  if (owner) {
    bb[0][0] = b_r[dd[0]]; bb[0][1] = b_r[dd[1]];
    bb[1][0] = b_z[dd[0]]; bb[1][1] = b_z[dd[1]];
    bb[2][0] = b_h[dd[0]]; bb[2][1] = b_h[dd[1]];
  }
  __syncthreads();   // full drain once: chunk-0 loads + LDS init visible

  // ---- pipelined per-step state (t=0: cor[b,0]==0 always -> ieff=0, rows stable)
  float a_c = sA[0];
  int c0 = sCor[0];
  int ieff_c = (c0 == 0) ? 0 : c0;
  bool pf_c = true;
  f16x8 af2 = *(const f16x8*)&hist[ieff_c * NH + q8];
  f16x8 af3 = *(const f16x8*)&hist[ieff_c * NH + 32 + q8];

  for (int t = 0; t < NL; ++t) {
    const int par = t & 1;
    const float a = a_c;
    const float oma = 1.f - a;
    const int ieff = ieff_c;
    const int cur = (t >> 4) & 1;
    const int tin = t & 15;

    // ---- issue next X chunk (once per 16 steps) ----
    if ((t & 15) == 0 && t + CH < NL && w < 3) {
      const _Float16* src = wsX + (size_t)w * BLD + (rowb + t + CH) * ND + lane * 8;
      _Float16* dst = &Xl[(cur ^ 1) * (3 * CH * ND) + w * (CH * ND)];
#pragma unroll
      for (int i = 0; i < 4; ++i)
        gload_lds16(src + i * 512, dst + i * 512);
    }

    // ---- hist frags: prefetched last step unless row==t (written last step)
    if (!pf_c) {
      af2 = *(const f16x8*)&hist[ieff * NH + q8];
      af3 = *(const f16x8*)&hist[ieff * NH + 32 + q8];
    }
    f16x8 af0 = *(const f16x8*)&hprev16[par][q8];
    f16x8 af1 = *(const f16x8*)&hprev16[par][32 + q8];

    // ---- X + md reads for this step (owner lanes; from LDS) ----
    float xv[3][2], md[2];
    if (owner) {
      const _Float16* xp = &Xl[cur * (3 * CH * ND) + tin * ND];
#pragma unroll
      for (int g = 0; g < 3; ++g) {
        xv[g][0] = (float)xp[g * (CH * ND) + dd[0]];
        xv[g][1] = (float)xp[g * (CH * ND) + dd[1]];
      }
      if (w < 2) {
        md[0] = a * hprev32[par][dd[0]];
        md[1] = a * hprev32[par][dd[1]];
      } else if (ieff == t) {
        md[0] = oma * hprev32[par][dd[0]];
        md[1] = oma * hprev32[par][dd[1]];
      } else {
        md[0] = oma * (float)hist[ieff * NH + (dd[0] - NH)];
        md[1] = oma * (float)hist[ieff * NH + (dd[1] - NH)];
      }
    }

    // ---- MFMA: lo (k<64) and hi (k>=64) accumulators ----
    f32x4 accL[3][2], accH[3][2];
#pragma unroll
    for (int g = 0; g < 3; ++g)
#pragma unroll
      for (int tt = 0; tt < 2; ++tt) {
        accL[g][tt] = (f32x4){0.f, 0.f, 0.f, 0.f};
        accH[g][tt] = (f32x4){0.f, 0.f, 0.f, 0.f};
      }
#pragma unroll
    for (int g = 0; g < 3; ++g)
#pragma unroll
      for (int tt = 0; tt < 2; ++tt) {
        accL[g][tt] = __builtin_amdgcn_mfma_f32_16x16x32_f16(af0, bf[g][tt][0], accL[g][tt], 0, 0, 0);
        accH[g][tt] = __builtin_amdgcn_mfma_f32_16x16x32_f16(af2, bf[g][tt][2], accH[g][tt], 0, 0, 0);
        accL[g][tt] = __builtin_amdgcn_mfma_f32_16x16x32_f16(af1, bf[g][tt][1], accL[g][tt], 0, 0, 0);
        accH[g][tt] = __builtin_amdgcn_mfma_f32_16x16x32_f16(af3, bf[g][tt][3], accH[g][tt], 0, 0, 0);
      }

    // ---- prefetch step-(t+1) state (overlaps MFMA/epilogue) ----
    const int tn = (t < NL - 1) ? t + 1 : t;
    float a_n = sA[tn];
    int c_n = sCor[tn];
    int ieff_n = (c_n == 0) ? tn : c_n;
    bool pf_n = (ieff_n <= t);         // row stable during this step?
    f16x8 af2n, af3n;
    if (pf_n) {
      af2n = *(const f16x8*)&hist[ieff_n * NH + q8];
      af3n = *(const f16x8*)&hist[ieff_n * NH + 32 + q8];
    }

    // ---- epilogue (owner lanes; row 0 of C => quad 0, reg 0) ----
    if (owner) {
#pragma unroll
      for (int tt = 0; tt < 2; ++tt) {
        float dr = a * accL[0][tt][0] + oma * accH[0][tt][0];
        float dz = a * accL[1][tt][0] + oma * accH[1][tt][0];
        float dh = a * accL[2][tt][0] + oma * accH[2][tt][0];
        float rr = 1.f / (1.f + __expf(-(xv[0][tt] + bb[0][tt] + dr)));
        float zz = 1.f / (1.f + __expf(-(xv[1][tt] + bb[1][tt] + dz)));
        float e2 = __expf(2.f * (xv[2][tt] + bb[2][tt] + rr * dh));
        float hh = (e2 - 1.f) / (e2 + 1.f);
        float h = (1.f - zz) * md[tt] + zz * hh;
        int d = dd[tt];
        out[(rowb + t) * ND + d] = h;      // never drained per-step
        hprev32[par ^ 1][d] = h;
        if (d < NH) hprev16[par ^ 1][d] = (_Float16)h;
        else        hist[(t + 1) * NH + (d - NH)] = (_Float16)h;
      }
    }

    // ---- barrier: LDS drain only; vmcnt(0) only at chunk boundaries ----
    if ((t & 15) == 15) WAIT_VM0();
    BAR_LDS();

    a_c = a_n; ieff_c = ieff_n; pf_c = pf_n;
    if (pf_n) { af2 = af2n; af3 = af3n; }
  }
}

// =====================================================================
extern "C" void kernel_launch(void* const* d_in, const int* in_sizes, int n_in,
                              void* d_out, int out_size, void* d_ws, size_t ws_size,
                              hipStream_t stream) {
  (void)in_sizes; (void)n_in; (void)out_size; (void)ws_size;
  const float* x    = (const float*)d_in[0];
  const int*   cor  = (const int*)d_in[1];
  const float* w_r  = (const float*)d_in[2];
  const float* b_r  = (const float*)d_in[3];
  const float* u_r  = (const float*)d_in[4];
  const float* w_z  = (const float*)d_in[5];
  const float* b_z  = (const float*)d_in[6];
  const float* u_z  = (const float*)d_in[7];
  const float* w_h  = (const float*)d_in[8];
  const float* b_h  = (const float*)d_in[9];
  const float* u_h  = (const float*)d_in[10];
  const float* k1k2 = (const float*)d_in[11];

  _Float16* wsX = (_Float16*)d_ws;                       // 3*BL*ND f16 = 48 MB
  float* wsA = (float*)((char*)d_ws + 3 * BLD * 2);      // BL f32 = 256 KB

  ka_kernel<<<dim3(BL / 256), dim3(256), 0, stream>>>(x, k1k2, wsA);
  kproj_kernel<<<dim3(BL / 128, 3), dim3(256), 0, stream>>>(x, w_r, w_z, w_h, wsX);
  kscan_kernel<<<dim3(NB), dim3(256), 0, stream>>>(u_r, u_z, u_h, b_r, b_z, b_h,
                                                   cor, wsX, wsA, (float*)d_out);
}